// Round 7
// baseline (222.775 us; speedup 1.0000x reference)
//
#include <hip/hip_runtime.h>

// YOLO-style loss on MI355X — round 11: wave-specialized ideal streamer.
// pred:      [B, 8, 8, 8] f32   (B = 65536)
// label_rc:  [B, L, 2]    i32   (L = 16)
// label_box: [B, L, 3]    f32
// out:       [1] f32 = (coord + cond) / B
//
// Evidence so far: five structurally different kernels (R4/R6/R7/R8/R10)
// all pin at inferred yolo ~61-66 us, while VALU/MLP/BW models each predict
// <25 us. All five coupled the pred stream with the label machinery in the
// same waves (~115-130 VGPR, deep pipelines). R11 decouples:
//   - 2048 STREAM blocks: noobj = sum(.w^2) over B*128 float4, flat index
//     space, 16 nt dwordx4 in flight/thread, no LDS/atomics/labels. This is
//     byte-for-byte the access pattern that benches at 6.3 TB/s.
//   - 256 LABEL blocks (blockIdx 0..255, dispatched FIRST to overlap the
//     stream): ONE BATCH PER THREAD -> all 16 labels are thread-local, so
//     obj-mask dedup is a 64-bit register mask (no LDS, no atomics, no
//     owner election). rc as 8x int4; box + cell gathers pipelined in
//     4-label groups, 2 groups in flight; everything fully unrolled and
//     statically indexed (L==16 fast path; generic fallback for other L).
//   - label threads subtract the labeled cells' (p3^2+p7^2) once each;
//     stream adds all cells -> exact reference semantics, all linear.
// If even this pure-stream form pins at ~62 us, the floor is not
// kernel-addressable (harness-level effective-BW ceiling) -> ROOFLINE.

static constexpr float LAMBDA_COORD = 5.0f;
static constexpr float LAMBDA_NOOBJ = 0.5f;
static constexpr float EPS_F = 1e-9f;

#define NSTREAM_BLOCKS 2048

typedef float nfloat4 __attribute__((ext_vector_type(4)));

__device__ __forceinline__ float4 nt_ld4(const float4* p) {
    nfloat4 v = __builtin_nontemporal_load((const nfloat4*)p);
    return make_float4(v.x, v.y, v.z, v.w);
}

__device__ __forceinline__ float bbox_iou(float px, float py, float pr,
                                          float gx, float gy, float gr) {
    float l1 = px - pr, r1 = px + pr, t1 = py - pr, b1 = py + pr;
    float l2 = gx - gr, r2 = gx + gr, t2 = gy - gr, b2 = gy + gr;
    float iw = fmaxf(fminf(r1, r2) - fmaxf(l1, l2), 0.0f);
    float ih = fmaxf(fminf(b1, b2) - fmaxf(t1, t2), 0.0f);
    float inter = iw * ih;
    float a1 = (r1 - l1) * (b1 - t1);
    float a2 = (r2 - l2) * (b2 - t2);
    return inter / (a1 + a2 - inter + EPS_F);
}

// ---- label-path helpers (all statically indexed under full unroll) ----

// One label: cell c, gathered float4 pair (pa,pb), ground truth (GX,GY,GR).
#define LPROC(c, pa, pb, GX, GY, GR)                                           \
    {                                                                          \
        const float p0 = (pa).x, p1 = (pa).y, p2 = (pa).z, p3 = (pa).w;        \
        const float p4 = (pb).x, p5 = (pb).y, p6 = (pb).z, p7 = (pb).w;        \
        const float iou1 = bbox_iou(p0, p1, p2, (GX), (GY), (GR));             \
        const float iou2 = bbox_iou(p4, p5, p6, (GX), (GY), (GR));             \
        const bool  sw_ = iou2 > iou1;                                         \
        const float cx = sw_ ? p4 : p0;                                        \
        const float cy = sw_ ? p5 : p1;                                        \
        const float cr = sw_ ? p6 : p2;                                        \
        const float conf    = sw_ ? p7 : p3;                                   \
        const float un_conf = sw_ ? p3 : p7;                                   \
        const float bigger  = sw_ ? iou2 : iou1;                               \
        const float smaller = sw_ ? iou1 : iou2;                               \
        const float dx = cx - (GX), dy = cy - (GY), dr = cr - (GR);            \
        main_acc += LAMBDA_COORD * (dx * dx + dy * dy + dr * dr);              \
        const float d1 = bigger - conf;                                        \
        main_acc += d1 * d1;                                                   \
        const float d2 = smaller - un_conf;                                    \
        noobj_acc += d2 * d2;                                                  \
        const unsigned long long bit_ = 1ull << (c);                           \
        if (!(seen & bit_)) { seen |= bit_;                                    \
            noobj_acc -= (p3 * p3 + p7 * p7); }                                \
    }

// Issue group G (labels 4G..4G+3): 3 box float4 + 4 cell gathers (8 float4).
#define GIS(P, cA, cB, cC, cD, G)                                              \
    {                                                                          \
        P##f0 = boxp[3 * (G)];                                                 \
        P##f1 = boxp[3 * (G) + 1];                                             \
        P##f2 = boxp[3 * (G) + 2];                                             \
        P##g0a = pbase[(cA) * 2]; P##g0b = pbase[(cA) * 2 + 1];                \
        P##g1a = pbase[(cB) * 2]; P##g1b = pbase[(cB) * 2 + 1];                \
        P##g2a = pbase[(cC) * 2]; P##g2b = pbase[(cC) * 2 + 1];                \
        P##g3a = pbase[(cD) * 2]; P##g3b = pbase[(cD) * 2 + 1];                \
    }

// Process group G held in P (box component mapping: 12 packed floats).
#define GPROC(P, cA, cB, cC, cD)                                               \
    {                                                                          \
        LPROC(cA, P##g0a, P##g0b, P##f0.x, P##f0.y, P##f0.z)                   \
        LPROC(cB, P##g1a, P##g1b, P##f0.w, P##f1.x, P##f1.y)                   \
        LPROC(cC, P##g2a, P##g2b, P##f1.z, P##f1.w, P##f2.x)                   \
        LPROC(cD, P##g3a, P##g3b, P##f2.y, P##f2.z, P##f2.w)                   \
    }

__global__ __launch_bounds__(256) void yolo_loss_kernel(
    const float* __restrict__ pred,
    const int*   __restrict__ label_rc,
    const float* __restrict__ label_box,
    float* __restrict__ partials,
    int B, int L, int nlabel)
{
    const int tid = threadIdx.x;
    float acc = 0.0f;

    if ((int)blockIdx.x < nlabel) {
        // ================= LABEL PATH: one batch per thread =================
        const long b = (long)blockIdx.x * 256 + tid;
        if (b < (long)B) {
            float main_acc = 0.0f, noobj_acc = 0.0f;
            unsigned long long seen = 0ull;
            const float4* pbase = (const float4*)(pred + (size_t)b * 512);

            if (L == 16) {
                const int4* rcp = (const int4*)(label_rc + (size_t)b * 32);
                const int4 r0 = rcp[0], r1 = rcp[1], r2 = rcp[2], r3 = rcp[3];
                const int4 r4 = rcp[4], r5 = rcp[5], r6 = rcp[6], r7 = rcp[7];
                const int c0  = r0.x * 8 + r0.y, c1  = r0.z * 8 + r0.w;
                const int c2  = r1.x * 8 + r1.y, c3  = r1.z * 8 + r1.w;
                const int c4  = r2.x * 8 + r2.y, c5  = r2.z * 8 + r2.w;
                const int c6  = r3.x * 8 + r3.y, c7  = r3.z * 8 + r3.w;
                const int c8  = r4.x * 8 + r4.y, c9  = r4.z * 8 + r4.w;
                const int c10 = r5.x * 8 + r5.y, c11 = r5.z * 8 + r5.w;
                const int c12 = r6.x * 8 + r6.y, c13 = r6.z * 8 + r6.w;
                const int c14 = r7.x * 8 + r7.y, c15 = r7.z * 8 + r7.w;
                const float4* boxp = (const float4*)(label_box + (size_t)b * 48);

                float4 Af0, Af1, Af2, Ag0a, Ag0b, Ag1a, Ag1b, Ag2a, Ag2b, Ag3a, Ag3b;
                float4 Bf0, Bf1, Bf2, Bg0a, Bg0b, Bg1a, Bg1b, Bg2a, Bg2b, Bg3a, Bg3b;

                GIS(A, c0, c1, c2, c3, 0)      // 2 groups in flight
                GIS(B, c4, c5, c6, c7, 1)
                GPROC(A, c0, c1, c2, c3)
                GIS(A, c8, c9, c10, c11, 2)
                GPROC(B, c4, c5, c6, c7)
                GIS(B, c12, c13, c14, c15, 3)
                GPROC(A, c8, c9, c10, c11)
                GPROC(B, c12, c13, c14, c15)
            } else {
                for (int l = 0; l < L; ++l) {   // generic fallback (unused at L=16)
                    const int2 rc = *(const int2*)(label_rc + ((size_t)b * L + l) * 2);
                    const int c = rc.x * 8 + rc.y;
                    const float* lb = label_box + ((size_t)b * L + l) * 3;
                    const float gx = lb[0], gy = lb[1], gr = lb[2];
                    const float4 pa = pbase[c * 2], pb = pbase[c * 2 + 1];
                    float GX = gx, GY = gy, GR = gr;
                    LPROC(c, pa, pb, GX, GY, GR)
                }
            }
            acc = main_acc + LAMBDA_NOOBJ * noobj_acc;
        }
    } else {
        // ================ STREAM PATH: noobj = sum(.w^2) ================
        const long NS    = (long)NSTREAM_BLOCKS * 256;
        const long st    = ((long)blockIdx.x - nlabel) * 256 + tid;
        const long total = (long)B * 128;       // float4 count
        const float4* gp = (const float4*)pred;
        float nacc = 0.0f;

        if (st + 15 * NS < total) {             // fast path: all 16 in flight
            const float4 v0  = nt_ld4(gp + st);
            const float4 v1  = nt_ld4(gp + st + 1 * NS);
            const float4 v2  = nt_ld4(gp + st + 2 * NS);
            const float4 v3  = nt_ld4(gp + st + 3 * NS);
            const float4 v4  = nt_ld4(gp + st + 4 * NS);
            const float4 v5  = nt_ld4(gp + st + 5 * NS);
            const float4 v6  = nt_ld4(gp + st + 6 * NS);
            const float4 v7  = nt_ld4(gp + st + 7 * NS);
            const float4 v8  = nt_ld4(gp + st + 8 * NS);
            const float4 v9  = nt_ld4(gp + st + 9 * NS);
            const float4 v10 = nt_ld4(gp + st + 10 * NS);
            const float4 v11 = nt_ld4(gp + st + 11 * NS);
            const float4 v12 = nt_ld4(gp + st + 12 * NS);
            const float4 v13 = nt_ld4(gp + st + 13 * NS);
            const float4 v14 = nt_ld4(gp + st + 14 * NS);
            const float4 v15 = nt_ld4(gp + st + 15 * NS);
            nacc = v0.w * v0.w + v1.w * v1.w + v2.w * v2.w + v3.w * v3.w
                 + v4.w * v4.w + v5.w * v5.w + v6.w * v6.w + v7.w * v7.w
                 + v8.w * v8.w + v9.w * v9.w + v10.w * v10.w + v11.w * v11.w
                 + v12.w * v12.w + v13.w * v13.w + v14.w * v14.w + v15.w * v15.w;
        } else {                                // boundary stragglers
            for (long i = st; i < total; i += NS) {
                const float4 v = nt_ld4(gp + i);
                nacc += v.w * v.w;
            }
        }
        acc = LAMBDA_NOOBJ * nacc;
    }

    // ---- wave + block reduction -> one partial per block ----
    #pragma unroll
    for (int off = 32; off > 0; off >>= 1)
        acc += __shfl_xor(acc, off);

    __shared__ float wsum[4];
    const int lane = tid & 63, wv = tid >> 6;
    if (lane == 0) wsum[wv] = acc;
    __syncthreads();
    if (tid == 0)
        partials[blockIdx.x] = wsum[0] + wsum[1] + wsum[2] + wsum[3];
}

__global__ __launch_bounds__(256) void reduce_kernel(
    const float* __restrict__ partials, float* __restrict__ out,
    int n, float invB)
{
    float s = 0.0f;
    for (int i = threadIdx.x; i < n; i += 256)
        s += partials[i];
    #pragma unroll
    for (int off = 32; off > 0; off >>= 1)
        s += __shfl_xor(s, off);

    __shared__ float wsum[4];
    const int lane = threadIdx.x & 63, w = threadIdx.x >> 6;
    if (lane == 0) wsum[w] = s;
    __syncthreads();
    if (threadIdx.x == 0)
        out[0] = (wsum[0] + wsum[1] + wsum[2] + wsum[3]) * invB;
}

extern "C" void kernel_launch(void* const* d_in, const int* in_sizes, int n_in,
                              void* d_out, int out_size, void* d_ws, size_t ws_size,
                              hipStream_t stream) {
    const float* pred      = (const float*)d_in[0];
    const int*   label_rc  = (const int*)d_in[1];
    const float* label_box = (const float*)d_in[2];
    float*       out       = (float*)d_out;
    float*       partials  = (float*)d_ws;

    const int B = in_sizes[0] / 512;          // G*G*C = 8*8*8
    const int L = in_sizes[1] / (B * 2);      // labels per batch (16)
    const float invB = 1.0f / (float)B;

    const int nlabel = (B + 255) / 256;       // 256 label blocks for B=65536
    const int blocks = nlabel + NSTREAM_BLOCKS;

    yolo_loss_kernel<<<blocks, 256, 0, stream>>>(
        pred, label_rc, label_box, partials, B, L, nlabel);

    reduce_kernel<<<1, 256, 0, stream>>>(partials, out, blocks, invB);
}

// Round 8
// 204.450 us; speedup vs baseline: 1.0896x; 1.0896x over previous
//
#include <hip/hip_runtime.h>

// YOLO-style loss on MI355X — round 12: revert to R10 (empirical best,
// 204.9 us wall), which is the session's terminal kernel.
// pred:      [B, 8, 8, 8] f32   (B = 65536)
// label_rc:  [B, L, 2]    i32   (L = 16)
// label_box: [B, L, 3]    f32
// out:       [1] f32 = (coord + cond) / B
//
// ROOFLINE ACCOUNTING (six structures, R4-R11): the harness's per-iteration
// reset enqueues a 512 MiB poison fill + ~148 MB input restores ahead of
// this kernel. Dispatch completion only requires writes to reach LLC, so
// ~256 MB of dirty reset debt drains to HBM DURING our window; our window
// is drain-dominated (~55 us) regardless of kernel structure. Demand-side
// models for this kernel are ~25-30 us; measured six structurally distinct
// kernels all pin at ~61-79 us. Iteration floor = (537 fill + ~296 restore
// + ~148 ours) MB / 6.9 TB/s + ~60 us fixed small-dispatch overhead
// ~= 203 us; this kernel measures 204.9 us.
//
// Kernel: counted-vmcnt register pipeline (R8) + non-temporal loads (R10).
//   per super i: wait labels(i) -> issue gather(i) -> issue labels(i+1)
//   then pred(i+1) -> noobj waits pred(i) -> IoU waits gather(i);
//   the bulk pred stream never drains. Dedup: one ds_or_rtn per label.

static constexpr float LAMBDA_COORD = 5.0f;
static constexpr float LAMBDA_NOOBJ = 0.5f;
static constexpr float EPS_F = 1e-9f;

#define WAVES_PER_BLOCK 4
#define SUPER   4         // batches per super-iteration (one per 16-lane group)
#define NBLOCKS 1024      // 4096 waves; 4 blocks/CU resident; 4 supers/wave

typedef float nfloat4 __attribute__((ext_vector_type(4)));
typedef int   nint2   __attribute__((ext_vector_type(2)));

__device__ __forceinline__ float4 nt_ld4(const float4* p) {
    nfloat4 v = __builtin_nontemporal_load((const nfloat4*)p);
    return make_float4(v.x, v.y, v.z, v.w);
}
__device__ __forceinline__ int2 nt_ld2i(const int* p) {
    nint2 v = __builtin_nontemporal_load((const nint2*)p);
    return make_int2(v.x, v.y);
}
__device__ __forceinline__ float nt_ldf(const float* p) {
    return __builtin_nontemporal_load(p);
}

__device__ __forceinline__ float bbox_iou(float px, float py, float pr,
                                          float gx, float gy, float gr) {
    float l1 = px - pr, r1 = px + pr, t1 = py - pr, b1 = py + pr;
    float l2 = gx - gr, r2 = gx + gr, t2 = gy - gr, b2 = gy + gr;
    float iw = fmaxf(fminf(r1, r2) - fmaxf(l1, l2), 0.0f);
    float ih = fmaxf(fminf(b1, b2) - fmaxf(t1, t2), 0.0f);
    float inter = iw * ih;
    float a1 = (r1 - l1) * (b1 - t1);
    float a2 = (r2 - l2) * (b2 - t2);
    return inter / (a1 + a2 - inter + EPS_F);
}

// Per-super register state.
#define DECL_SUPER(S)                                                          \
    float4 S##_q0, S##_q1, S##_q2, S##_q3, S##_q4, S##_q5, S##_q6, S##_q7;     \
    int2   S##_rc   = make_int2(0, 0);                                         \
    float  S##_gx = 0.f, S##_gy = 0.f, S##_gr = 0.f;                           \
    int    S##_ok = 0, S##_cell = 0;                                           \
    float4 S##_c0 = make_float4(0.f, 0.f, 0.f, 0.f);                           \
    float4 S##_c1 = make_float4(0.f, 0.f, 0.f, 0.f);

// Issue super g's loads: labels FIRST (so next iteration's label wait is a
// short queue prefix), then the 8-dwordx4 pred stream. All non-temporal.
#define LOAD_SUPER(S, g)                                                       \
    {                                                                          \
        const long bb_ = (long)(g) * SUPER;                                    \
        const long bq_ = bb_ + grp;                                            \
        S##_ok = (bq_ < (long)B) && (lj < L);                                  \
        if (S##_ok) {                                                          \
            S##_rc = nt_ld2i(label_rc + ((size_t)bq_ * L + lj) * 2);           \
            const float* lb_ = label_box + ((size_t)bq_ * L + lj) * 3;         \
            S##_gx = nt_ldf(lb_ + 0);                                          \
            S##_gy = nt_ldf(lb_ + 1);                                          \
            S##_gr = nt_ldf(lb_ + 2);                                          \
        }                                                                      \
        const float4* gp_ = (const float4*)(pred + bb_ * 512);                 \
        if (bb_ + SUPER <= (long)B) {          /* fast path: full super */     \
            S##_q0 = nt_ld4(gp_ + lane);        S##_q1 = nt_ld4(gp_ + lane + 64);  \
            S##_q2 = nt_ld4(gp_ + lane + 128);  S##_q3 = nt_ld4(gp_ + lane + 192); \
            S##_q4 = nt_ld4(gp_ + lane + 256);  S##_q5 = nt_ld4(gp_ + lane + 320); \
            S##_q6 = nt_ld4(gp_ + lane + 384);  S##_q7 = nt_ld4(gp_ + lane + 448); \
        } else {                                                               \
            const float4 z_ = make_float4(0.f, 0.f, 0.f, 0.f);                 \
            S##_q0 = S##_q1 = S##_q2 = S##_q3 = z_;                            \
            S##_q4 = S##_q5 = S##_q6 = S##_q7 = z_;                            \
            if (bb_ + 0 < (long)B) { S##_q0 = nt_ld4(gp_ + lane);       S##_q1 = nt_ld4(gp_ + lane + 64);  } \
            if (bb_ + 1 < (long)B) { S##_q2 = nt_ld4(gp_ + lane + 128); S##_q3 = nt_ld4(gp_ + lane + 192); } \
            if (bb_ + 2 < (long)B) { S##_q4 = nt_ld4(gp_ + lane + 256); S##_q5 = nt_ld4(gp_ + lane + 320); } \
            if (bb_ + 3 < (long)B) { S##_q6 = nt_ld4(gp_ + lane + 384); S##_q7 = nt_ld4(gp_ + lane + 448); } \
        }                                                                      \
    }

// Consume super g's LABELS only (short prefix wait), reset the dedup mask,
// and issue the 2-dwordx4 responsible-cell gather (lines are cache-hot:
// streamed by this wave moments ago; nt = last use).
#define GATHER_SUPER(S, g)                                                     \
    {                                                                          \
        if (lane < SUPER * 2) my_mask[lane] = 0u;                              \
        if (S##_ok) {                                                          \
            S##_cell = S##_rc.x * 8 + S##_rc.y;         /* 0..63 */            \
            const long bq_ = (long)(g) * SUPER + grp;                          \
            const float4* cp_ =                                                \
                (const float4*)(pred + (size_t)bq_ * 512 + (size_t)S##_cell * 8); \
            S##_c0 = nt_ld4(cp_ + 0);                                          \
            S##_c1 = nt_ld4(cp_ + 1);                                          \
        }                                                                      \
    }

// Full processing of super g: noobj sum (waits pred(g), prefix), dedup
// atomic, IoU + losses (waits gather(g), prefix; stream stays in flight).
#define PROC_SUPER(S)                                                          \
    {                                                                          \
        noobj_acc += S##_q0.w * S##_q0.w + S##_q1.w * S##_q1.w                 \
                   + S##_q2.w * S##_q2.w + S##_q3.w * S##_q3.w                 \
                   + S##_q4.w * S##_q4.w + S##_q5.w * S##_q5.w                 \
                   + S##_q6.w * S##_q6.w + S##_q7.w * S##_q7.w;                \
        if (S##_ok) {                                                          \
            const unsigned bit_ = 1u << (S##_cell & 31);                       \
            const unsigned old_ =                                              \
                atomicOr(&my_mask[grp * 2 + (S##_cell >> 5)], bit_);           \
            const float p0 = S##_c0.x, p1 = S##_c0.y, p2 = S##_c0.z, p3 = S##_c0.w; \
            const float p4 = S##_c1.x, p5 = S##_c1.y, p6 = S##_c1.z, p7 = S##_c1.w; \
            const float iou1 = bbox_iou(p0, p1, p2, S##_gx, S##_gy, S##_gr);   \
            const float iou2 = bbox_iou(p4, p5, p6, S##_gx, S##_gy, S##_gr);   \
            const bool  sw_ = iou2 > iou1;                                     \
            const float cx = sw_ ? p4 : p0;                                    \
            const float cy = sw_ ? p5 : p1;                                    \
            const float cr = sw_ ? p6 : p2;                                    \
            const float conf    = sw_ ? p7 : p3;                               \
            const float un_conf = sw_ ? p3 : p7;                               \
            const float bigger  = sw_ ? iou2 : iou1;                           \
            const float smaller = sw_ ? iou1 : iou2;                           \
            const float dx = cx - S##_gx, dy = cy - S##_gy, dr = cr - S##_gr;  \
            main_acc += LAMBDA_COORD * (dx * dx + dy * dy + dr * dr);          \
            const float d1 = bigger - conf;                                    \
            main_acc += d1 * d1;                                               \
            const float d2 = smaller - un_conf;                                \
            noobj_acc += d2 * d2;                                              \
            if ((old_ & bit_) == 0u)     /* owner: subtract labeled cell */    \
                noobj_acc -= (p3 * p3 + p7 * p7);                              \
        }                                                                      \
    }

__global__ __launch_bounds__(256, 4) void yolo_loss_kernel(
    const float* __restrict__ pred,
    const int*   __restrict__ label_rc,
    const float* __restrict__ label_box,
    float* __restrict__ partials,
    int B, int L)
{
    __shared__ unsigned cmask[WAVES_PER_BLOCK][SUPER * 2];   // 128 B
    __shared__ float    wsum[WAVES_PER_BLOCK];

    const int tid  = threadIdx.x;
    const int lane = tid & 63;
    const int wv   = tid >> 6;
    const int grp  = lane >> 4;     // which batch of the super
    const int lj   = lane & 15;     // label index within that batch

    unsigned* my_mask = cmask[wv];

    const long waves_tot = (long)gridDim.x * WAVES_PER_BLOCK;
    const long wgid      = (long)blockIdx.x * WAVES_PER_BLOCK + wv;
    const long nsup      = ((long)B + SUPER - 1) / SUPER;
    const long spw       = (nsup + waves_tot - 1) / waves_tot;
    const long g_begin   = wgid * spw;
    const long g_end     = (g_begin + spw < nsup) ? (g_begin + spw) : nsup;

    float main_acc  = 0.0f;  // lambda_coord * coord + d1^2
    float noobj_acc = 0.0f;  // sum w^2 - owner(p3^2+p7^2) + d2^2 (x lambda at end)

    DECL_SUPER(A)
    DECL_SUPER(B)

    long g = g_begin;
    if (g < g_end) {
        LOAD_SUPER(A, g);
        while (true) {
            GATHER_SUPER(A, g);                        // wait labels(A) only
            if (g + 1 < g_end) LOAD_SUPER(B, g + 1);   // prefetch next
            PROC_SUPER(A);                             // stream stays in flight
            ++g; if (g >= g_end) break;
            GATHER_SUPER(B, g);
            if (g + 1 < g_end) LOAD_SUPER(A, g + 1);
            PROC_SUPER(B);
            ++g; if (g >= g_end) break;
        }
    }

    // ---- wave + block reduction -> one partial per block ----
    float acc = main_acc + LAMBDA_NOOBJ * noobj_acc;
    #pragma unroll
    for (int off = 32; off > 0; off >>= 1)
        acc += __shfl_xor(acc, off);
    if (lane == 0) wsum[wv] = acc;
    __syncthreads();
    if (tid == 0)
        partials[blockIdx.x] = wsum[0] + wsum[1] + wsum[2] + wsum[3];
}

__global__ __launch_bounds__(256) void reduce_kernel(
    const float* __restrict__ partials, float* __restrict__ out,
    int n, float invB)
{
    float s = 0.0f;
    for (int i = threadIdx.x; i < n; i += 256)
        s += partials[i];
    #pragma unroll
    for (int off = 32; off > 0; off >>= 1)
        s += __shfl_xor(s, off);

    __shared__ float wsum[4];
    const int lane = threadIdx.x & 63, w = threadIdx.x >> 6;
    if (lane == 0) wsum[w] = s;
    __syncthreads();
    if (threadIdx.x == 0)
        out[0] = (wsum[0] + wsum[1] + wsum[2] + wsum[3]) * invB;
}

extern "C" void kernel_launch(void* const* d_in, const int* in_sizes, int n_in,
                              void* d_out, int out_size, void* d_ws, size_t ws_size,
                              hipStream_t stream) {
    const float* pred      = (const float*)d_in[0];
    const int*   label_rc  = (const int*)d_in[1];
    const float* label_box = (const float*)d_in[2];
    float*       out       = (float*)d_out;
    float*       partials  = (float*)d_ws;

    const int B = in_sizes[0] / 512;          // G*G*C = 8*8*8
    const int L = in_sizes[1] / (B * 2);      // labels per batch (16)
    const float invB = 1.0f / (float)B;

    yolo_loss_kernel<<<NBLOCKS, 256, 0, stream>>>(
        pred, label_rc, label_box, partials, B, L);

    reduce_kernel<<<1, 256, 0, stream>>>(partials, out, NBLOCKS, invB);
}